// Round 10
// baseline (274.068 us; speedup 1.0000x reference)
//
#include <hip/hip_runtime.h>

typedef unsigned short u16;
typedef short bf16x8 __attribute__((ext_vector_type(8)));
typedef float f32x4 __attribute__((ext_vector_type(4)));
typedef const __attribute__((address_space(1))) void* gptr_t;
typedef __attribute__((address_space(3))) void* lptr_t;

#define B_   64
#define N_   393
#define C_   768
#define H_   12
#define HD_  64
#define P_   197
#define BIAS_N 416
#define PPAD 208
#define VTP  448
#define M_KV (B_ * N_)   // 25152
#define M_PR (B_ * P_)   // 12608
#define SCALE_L2E 0.180336879f   // 0.125 * log2(e)

__device__ __forceinline__ u16 f2bf(float f) {
    unsigned u = __float_as_uint(f);
    return (u16)((u + 0x7FFFu + ((u >> 16) & 1u)) >> 16);
}
__device__ __forceinline__ unsigned cvt_pk_bf16(float lo, float hi) {
    unsigned r;
    asm("v_cvt_pk_bf16_f32 %0, %1, %2" : "=v"(r) : "v"(lo), "v"(hi));
    return r;
}
__device__ __forceinline__ float exp2_fast(float x) {
    float r;
    asm("v_exp_f32 %0, %1" : "=v"(r) : "v"(x));
    return r;
}

// ---------------------------------------------------------------------------
// conv_all: fused fp32->bf16 for x, wk, wv, proj_w
// ---------------------------------------------------------------------------
__global__ __launch_bounds__(256) void conv_all(
    const float* __restrict__ x, const float* __restrict__ wk,
    const float* __restrict__ wv, const float* __restrict__ pw,
    u16* __restrict__ xh, u16* __restrict__ wkvh, u16* __restrict__ pwh)
{
    const int XN4 = 19316736 / 4;
    const int WN4 = 589824 / 4;
    int i = blockIdx.x * 256 + threadIdx.x;
    const float* src; u16* dst; int off;
    if (i < XN4) { src = x; dst = xh; off = i; }
    else {
        int j = i - XN4;
        int sec = j / WN4;
        off = j - sec * WN4;
        src = sec == 0 ? wk : (sec == 1 ? wv : pw);
        dst = sec == 0 ? wkvh : (sec == 1 ? wkvh + 589824 : pwh);
    }
    float4 v = ((const float4*)src)[off];
    u16 o[4] = {f2bf(v.x), f2bf(v.y), f2bf(v.z), f2bf(v.w)};
    *(uint2*)(dst + off * 4) = *(uint2*)o;
}

// ---------------------------------------------------------------------------
// vzero: Vt[:, 393:448) = 0  (finite guard for PV tail reads)
// grid 12288 x 256: idx -> row = idx>>6 (b*768+dg), col = idx&63 (<55)
// ---------------------------------------------------------------------------
__global__ __launch_bounds__(256) void vzero_kernel(u16* __restrict__ Vt)
{
    int idx = blockIdx.x * 256 + threadIdx.x;
    int row = idx >> 6, c = idx & 63;
    if (c < 55)
        Vt[(size_t)row * VTP + 393 + c] = 0;
}

// ---------------------------------------------------------------------------
// prep1 / prep2 (unchanged)
// ---------------------------------------------------------------------------
__global__ __launch_bounds__(256) void prep1_kernel(
    const float* __restrict__ q_learned, const float* __restrict__ pos_embed,
    const float* __restrict__ rpe_w, u16* __restrict__ qh, float* __restrict__ lk)
{
    __shared__ float q_s[C_];
    const int p = blockIdx.x, t = threadIdx.x;
    for (int c = t; c < C_; c += 256) {
        float v = q_learned[c] + pos_embed[p * C_ + c];
        q_s[c] = v;
        qh[p * C_ + c] = f2bf(v);
    }
    __syncthreads();
    if (t < H_ * 8) {
        int h = t >> 3, u = t & 7;
        float s = 0.f;
        #pragma unroll 8
        for (int d = 0; d < HD_; ++d)
            s = fmaf(q_s[h * HD_ + d], rpe_w[d * 8 + u], s);
        lk[(h * P_ + p) * 8 + u] = s;
    }
}

__global__ __launch_bounds__(256) void prep2_kernel(
    const float* __restrict__ lk, const int* __restrict__ rp_bucket,
    float* __restrict__ biasT)
{
    int bx = blockIdx.x;
    int h = bx / N_, j = bx % N_;
    int t = threadIdx.x;
    if (t >= PPAD) return;
    int jm;
    if (j == 0) jm = 0;
    else { jm = j - 1; if (jm >= 196) jm -= 196; jm += 1; }
    float v = 0.f;
    if (t < P_) {
        int bucket = rp_bucket[t * P_ + jm];
        v = lk[(h * P_ + t) * 8 + bucket] * 1.44269504f;
    }
    biasT[((size_t)h * BIAS_N + j) * PPAD + t] = v;
}

// ---------------------------------------------------------------------------
// gemm_kv: 128x128x64 m97 structure (r8 known-good core) with fused epilogues:
//   K-half (n0<768): Kh[((b*12+h)*393 + j)*64 + dl]  (32B coalesced runs)
//   V-half: transpose via LDS (reuse As/Bs pool; 2 token-half passes), then
//   8-aligned 16B stores along j per b-segment; masked scalar edges.
// ---------------------------------------------------------------------------
__global__ __launch_bounds__(256) void gemm_kv(
    const u16* __restrict__ A, const u16* __restrict__ Bw,
    u16* __restrict__ Kh, u16* __restrict__ Vt)
{
    __shared__ __align__(16) u16 pool[16384];   // 32 KB; As=[0,8192), Bs=[8192,16384)
    u16* As = pool;
    u16* Bs = pool + 8192;

    const int gx = gridDim.x;
    const int nwg = gx * gridDim.y;
    const int orig = blockIdx.y * gx + blockIdx.x;
    const int xcd = orig & 7, rank = orig >> 3;
    const int q = nwg >> 3, r = nwg & 7;
    const int wgid = (xcd < r ? xcd * (q + 1) : r * (q + 1) + (xcd - r) * q) + rank;
    const int n0 = (wgid % gx) * 128;
    const int m0 = (wgid / gx) * 128;

    const int t = threadIdx.x;
    const int w = t >> 6, l = t & 63;
    const int wr = w >> 1, wc = w & 1;
    const int l15 = l & 15, lg = l >> 4;
    const int lrow = l >> 3, lslot = l & 7;
    const int Mc = M_KV - 1;

    f32x4 acc[4][4];
    #pragma unroll
    for (int i = 0; i < 4; ++i)
        #pragma unroll
        for (int j = 0; j < 4; ++j) acc[i][j] = (f32x4){0.f, 0.f, 0.f, 0.f};

    for (int ks = 0; ks < 12; ++ks) {
        const int k0 = ks * 64;
        if (ks) __syncthreads();
        #pragma unroll
        for (int i = 0; i < 4; ++i) {
            const int rbase = w * 32 + i * 8;
            int arow = m0 + rbase + lrow; if (arow > Mc) arow = Mc;
            const int brow = n0 + rbase + lrow;
            const u16* ga = A  + (size_t)arow * 768 + k0 + lslot * 8;
            const u16* gb = Bw + (size_t)brow * 768 + k0 + lslot * 8;
            __builtin_amdgcn_global_load_lds((gptr_t)(const void*)ga,
                                             (lptr_t)(void*)(As + rbase * 64), 16, 0, 0);
            __builtin_amdgcn_global_load_lds((gptr_t)(const void*)gb,
                                             (lptr_t)(void*)(Bs + rbase * 64), 16, 0, 0);
        }
        __syncthreads();
        #pragma unroll
        for (int kk = 0; kk < 2; ++kk) {
            bf16x8 af[4], bfr[4];
            #pragma unroll
            for (int mf = 0; mf < 4; ++mf) {
                af[mf]  = *(const bf16x8*)(As + (wr * 64 + mf * 16 + l15) * 64 + (kk * 4 + lg) * 8);
                bfr[mf] = *(const bf16x8*)(Bs + (wc * 64 + mf * 16 + l15) * 64 + (kk * 4 + lg) * 8);
            }
            #pragma unroll
            for (int mf = 0; mf < 4; ++mf)
                #pragma unroll
                for (int nf = 0; nf < 4; ++nf)
                    acc[mf][nf] = __builtin_amdgcn_mfma_f32_16x16x32_bf16(
                        af[mf], bfr[nf], acc[mf][nf], 0, 0, 0);
        }
    }

    if (n0 < 768) {
        // -------- K epilogue: per-head dense layout --------
        #pragma unroll
        for (int mf = 0; mf < 4; ++mf) {
            int mbase = m0 + wr * 64 + mf * 16 + lg * 4;
            #pragma unroll
            for (int rr = 0; rr < 4; ++rr) {
                int m = mbase + rr;
                if (m < M_KV) {
                    int bb = m / 393;
                    int jj = m - bb * 393;
                    #pragma unroll
                    for (int nf = 0; nf < 4; ++nf) {
                        int col = n0 + wc * 64 + nf * 16 + l15;
                        int hh = col >> 6, dl = col & 63;
                        Kh[((size_t)(bb * 12 + hh) * 393 + jj) * 64 + dl] =
                            f2bf(acc[mf][nf][rr]);
                    }
                }
            }
        }
    } else {
        // -------- V epilogue: LDS transpose, j-aligned stores --------
        const int dg0 = n0 - 768;
        #pragma unroll
        for (int ph = 0; ph < 2; ++ph) {
            __syncthreads();   // pool free: K-loop reads (ph0) / prior pass reads (ph1) done
            if (wr == ph) {
                #pragma unroll
                for (int mf = 0; mf < 4; ++mf)
                    #pragma unroll
                    for (int nf = 0; nf < 4; ++nf) {
                        int dim = wc * 64 + nf * 16 + l15;
                        int tokr = mf * 16 + lg * 4;
                        unsigned v01 = cvt_pk_bf16(acc[mf][nf][0], acc[mf][nf][1]);
                        unsigned v23 = cvt_pk_bf16(acc[mf][nf][2], acc[mf][nf][3]);
                        *(unsigned*)(pool + dim * 72 + tokr)     = v01;
                        *(unsigned*)(pool + dim * 72 + tokr + 2) = v23;
                    }
            }
            __syncthreads();
            const int T0 = m0 + ph * 64;
            if (T0 < M_KV) {
                int b0 = T0 / 393, J0 = T0 - 393 * b0;
                int S = 393 - J0; if (S > 64) S = 64;
                #pragma unroll
                for (int seg = 0; seg < 2; ++seg) {
                    int bb  = b0 + seg;
                    int ja  = seg ? 0      : J0;
                    int len = seg ? 64 - S : S;
                    int tr0 = seg ? S      : -J0;   // tok_rel = tr0 + j
                    if (bb >= B_ || len <= 0) continue;
                    int jc0 = ja & ~7;
                    int nch = ((ja + len + 7) >> 3) - (jc0 >> 3);
                    for (int i = t; i < 128 * 16; i += 256) {
                        int ci = i & 15, dim = i >> 4;
                        if (ci >= nch) continue;
                        int jc = jc0 + ci * 8;
                        bool full = (jc >= ja) && (jc + 8 <= ja + len);
                        u16 vals[8];
                        #pragma unroll
                        for (int k = 0; k < 8; ++k) {
                            int j = jc + k;
                            int tr = tr0 + j;
                            tr = tr < 0 ? 0 : (tr > 63 ? 63 : tr);
                            u16 v = pool[dim * 72 + tr];
                            vals[k] = (j >= ja && j < ja + len) ? v : (u16)0;
                        }
                        u16* dst = Vt + (size_t)(bb * 768 + dg0 + dim) * VTP;
                        if (full) {
                            *(bf16x8*)(dst + jc) = *(bf16x8*)vals;   // jc 8-aligned
                        } else {
                            #pragma unroll
                            for (int k = 0; k < 8; ++k) {
                                int j = jc + k;
                                if (j >= ja && j < ja + len) dst[j] = vals[k];
                            }
                        }
                    }
                }
            }
        }
    }
}

// ---------------------------------------------------------------------------
// proj GEMM: m97 structure (known-good)
// ---------------------------------------------------------------------------
__global__ __launch_bounds__(256) void gemm_proj(
    const u16* __restrict__ A, const u16* __restrict__ Bw,
    float* __restrict__ Cf, const float* __restrict__ bias)
{
    __shared__ __align__(16) u16 As[128 * 64];
    __shared__ __align__(16) u16 Bs[128 * 64];

    const int gx = gridDim.x;
    const int nwg = gx * gridDim.y;
    const int orig = blockIdx.y * gx + blockIdx.x;
    const int xcd = orig & 7, rank = orig >> 3;
    const int q = nwg >> 3, r = nwg & 7;
    const int wgid = (xcd < r ? xcd * (q + 1) : r * (q + 1) + (xcd - r) * q) + rank;
    const int n0 = (wgid % gx) * 128;
    const int m0 = (wgid / gx) * 128;

    const int t = threadIdx.x;
    const int w = t >> 6, l = t & 63;
    const int wr = w >> 1, wc = w & 1;
    const int l15 = l & 15, lg = l >> 4;
    const int lrow = l >> 3, lslot = l & 7;
    const int Mc = M_PR - 1;

    f32x4 acc[4][4];
    #pragma unroll
    for (int i = 0; i < 4; ++i)
        #pragma unroll
        for (int j = 0; j < 4; ++j) acc[i][j] = (f32x4){0.f, 0.f, 0.f, 0.f};

    for (int ks = 0; ks < 12; ++ks) {
        const int k0 = ks * 64;
        if (ks) __syncthreads();
        #pragma unroll
        for (int i = 0; i < 4; ++i) {
            const int rbase = w * 32 + i * 8;
            int arow = m0 + rbase + lrow; if (arow > Mc) arow = Mc;
            const int brow = n0 + rbase + lrow;
            const u16* ga = A  + (size_t)arow * 768 + k0 + lslot * 8;
            const u16* gb = Bw + (size_t)brow * 768 + k0 + lslot * 8;
            __builtin_amdgcn_global_load_lds((gptr_t)(const void*)ga,
                                             (lptr_t)(void*)(As + rbase * 64), 16, 0, 0);
            __builtin_amdgcn_global_load_lds((gptr_t)(const void*)gb,
                                             (lptr_t)(void*)(Bs + rbase * 64), 16, 0, 0);
        }
        __syncthreads();
        #pragma unroll
        for (int kk = 0; kk < 2; ++kk) {
            bf16x8 af[4], bfr[4];
            #pragma unroll
            for (int mf = 0; mf < 4; ++mf) {
                af[mf]  = *(const bf16x8*)(As + (wr * 64 + mf * 16 + l15) * 64 + (kk * 4 + lg) * 8);
                bfr[mf] = *(const bf16x8*)(Bs + (wc * 64 + mf * 16 + l15) * 64 + (kk * 4 + lg) * 8);
            }
            #pragma unroll
            for (int mf = 0; mf < 4; ++mf)
                #pragma unroll
                for (int nf = 0; nf < 4; ++nf)
                    acc[mf][nf] = __builtin_amdgcn_mfma_f32_16x16x32_bf16(
                        af[mf], bfr[nf], acc[mf][nf], 0, 0, 0);
        }
    }

    #pragma unroll
    for (int mf = 0; mf < 4; ++mf)
        #pragma unroll
        for (int nf = 0; nf < 4; ++nf) {
            int col = n0 + wc * 64 + nf * 16 + l15;
            float bb = bias[col];
            #pragma unroll
            for (int rr = 0; rr < 4; ++rr) {
                int m = m0 + wr * 64 + mf * 16 + lg * 4 + rr;
                if (m < M_PR) Cf[(size_t)m * 768 + col] = acc[mf][nf][rr] + bb;
            }
        }
}

// ---------------------------------------------------------------------------
// attention (r9 trim) with dense per-head K layout
// ---------------------------------------------------------------------------
__global__ __launch_bounds__(256, 2) void attn_mfma5(
    const u16* __restrict__ qh, const u16* __restrict__ Kh,
    const u16* __restrict__ Vt, const float* __restrict__ biasT,
    u16* __restrict__ Obuf)
{
    __shared__ __align__(16) u16 pts[64 * 456];
    __shared__ __align__(16) u16 kvs[2][64 * 64];

    const int id = blockIdx.x;
    const int work = (id & 7) * 384 + (id >> 3);
    const int ptile = work & 3;
    const int rest = work >> 2;
    const int h = rest % 12;
    const int b = rest / 12;
    const int p0 = ptile * 64;

    const int t = threadIdx.x, w = t >> 6, l = t & 63;
    const int l15 = l & 15, lg = l >> 4;
    const int p0w = p0 + w * 16;

    int srow[2], sslot[2], swoff[2];
    #pragma unroll
    for (int i = 0; i < 2; ++i) {
        int c = t + 256 * i;
        srow[i] = c >> 3; sslot[i] = c & 7;
        swoff[i] = srow[i] * 64 + ((sslot[i] ^ (srow[i] & 7)) << 3);
    }

    int prow = p0w + l15; if (prow > P_ - 1) prow = P_ - 1;
    const u16* qp = qh + (size_t)prow * C_ + h * HD_ + lg * 8;
    bf16x8 qf0 = *(const bf16x8*)(qp);
    bf16x8 qf1 = *(const bf16x8*)(qp + 32);

    const u16* Kbase = Kh + (size_t)(b * 12 + h) * (N_ * HD_);
    const u16* Vbase = Vt + (size_t)(b * H_ + h) * (HD_ * VTP);

    f32x4 acc[7][4];
    #pragma unroll
    for (int i = 0; i < 7; ++i)
        #pragma unroll
        for (int j = 0; j < 4; ++j) acc[i][j] = (f32x4){0.f, 0.f, 0.f, 0.f};

    // ---------------- pass 1: QK^T ----------------
    bf16x8 ra[2];
    #pragma unroll
    for (int i = 0; i < 2; ++i)
        ra[i] = *(const bf16x8*)(Kbase + srow[i] * 64 + sslot[i] * 8);
    #pragma unroll
    for (int i = 0; i < 2; ++i) *(bf16x8*)(&kvs[0][swoff[i]]) = ra[i];
    __syncthreads();

    #pragma unroll
    for (int nt = 0; nt < 7; ++nt) {
        const u16* kcur = kvs[nt & 1];
        if (nt < 6) {
            #pragma unroll
            for (int i = 0; i < 2; ++i) {
                int rn = (nt + 1) * 64 + srow[i]; if (rn > N_ - 1) rn = N_ - 1;
                ra[i] = *(const bf16x8*)(Kbase + rn * 64 + sslot[i] * 8);
            }
        }
        const int smax = (nt == 6) ? 1 : 4;
        __builtin_amdgcn_s_setprio(1);
        #pragma unroll
        for (int kc = 0; kc < 2; ++kc)
            #pragma unroll
            for (int sub = 0; sub < smax; ++sub) {
                int row = sub * 16 + l15;
                bf16x8 kb = *(const bf16x8*)(kcur + row * 64 + (((kc * 4 + lg) ^ (row & 7)) << 3));
                acc[nt][sub] = __builtin_amdgcn_mfma_f32_16x16x32_bf16(
                    kc ? qf1 : qf0, kb, acc[nt][sub], 0, 0, 0);
            }
        __builtin_amdgcn_s_setprio(0);
        if (nt < 6) {
            #pragma unroll
            for (int i = 0; i < 2; ++i) *(bf16x8*)(&kvs[(nt + 1) & 1][swoff[i]]) = ra[i];
        }
        __syncthreads();
    }

    // issue V tile 0 loads; softmax hides latency (T14)
    #pragma unroll
    for (int i = 0; i < 2; ++i)
        ra[i] = *(const bf16x8*)(Vbase + (size_t)srow[i] * VTP + sslot[i] * 8);

    // ---------------- single-pass softmax ----------------
    const int pcl = (p0w + lg * 4) > (PPAD - 4) ? (PPAD - 4) : (p0w + lg * 4);
    float s4[4] = {0.f, 0.f, 0.f, 0.f};
    #pragma unroll
    for (int nt = 0; nt < 7; ++nt) {
        const int smax = (nt == 6) ? 1 : 4;
        #pragma unroll
        for (int sub = 0; sub < smax; ++sub) {
            int n = nt * 64 + sub * 16 + l15;
            if (n < N_) {
                float4 b4 = *(const float4*)(biasT + ((size_t)h * BIAS_N + n) * PPAD + pcl);
                float bb[4] = {b4.x, b4.y, b4.z, b4.w};
                #pragma unroll
                for (int rr = 0; rr < 4; ++rr) {
                    float e = exp2_fast(fmaf(acc[nt][sub][rr], SCALE_L2E, bb[rr]));
                    acc[nt][sub][rr] = e;
                    s4[rr] += e;
                }
            } else {
                acc[nt][sub] = (f32x4){0.f, 0.f, 0.f, 0.f};
            }
        }
    }
    float rinv4[4];
    #pragma unroll
    for (int rr = 0; rr < 4; ++rr) {
        float s = s4[rr];
        s += __shfl_xor(s, 1); s += __shfl_xor(s, 2);
        s += __shfl_xor(s, 4); s += __shfl_xor(s, 8);
        rinv4[rr] = 1.0f / s;
    }

    // ---------------- P (unnormalized) -> LDS bf16 ----------------
    {
        const int rowb = w * 16 + lg * 4;
        #pragma unroll
        for (int nt = 0; nt < 7; ++nt) {
            const int smax = (nt == 6) ? 1 : 4;
            #pragma unroll
            for (int sub = 0; sub < smax; ++sub) {
                int col = nt * 64 + sub * 16 + l15;
                unsigned pk01 = cvt_pk_bf16(acc[nt][sub][0], acc[nt][sub][1]);
                unsigned pk23 = cvt_pk_bf16(acc[nt][sub][2], acc[nt][sub][3]);
                pts[(rowb + 0) * 456 + col] = (u16)pk01;
                pts[(rowb + 1) * 456 + col] = (u16)(pk01 >> 16);
                pts[(rowb + 2) * 456 + col] = (u16)pk23;
                pts[(rowb + 3) * 456 + col] = (u16)(pk23 >> 16);
            }
        }
        #pragma unroll
        for (int rr = 0; rr < 4; ++rr)
            pts[(rowb + rr) * 456 + 400 + l15] = 0;
    }
    #pragma unroll
    for (int i = 0; i < 2; ++i) *(bf16x8*)(&kvs[0][swoff[i]]) = ra[i];
    __syncthreads();

    // ---------------- pass 2: PV ----------------
    f32x4 o[4];
    #pragma unroll
    for (int i = 0; i < 4; ++i) o[i] = (f32x4){0.f, 0.f, 0.f, 0.f};

    #pragma unroll
    for (int nt = 0; nt < 7; ++nt) {
        const u16* kcur = kvs[nt & 1];
        if (nt < 6) {
            #pragma unroll
            for (int i = 0; i < 2; ++i)
                ra[i] = *(const bf16x8*)(Vbase + (size_t)srow[i] * VTP + (nt + 1) * 64 + sslot[i] * 8);
        }
        const int kcmax = (nt == 6) ? 1 : 2;
        __builtin_amdgcn_s_setprio(1);
        #pragma unroll
        for (int kc = 0; kc < kcmax; ++kc) {
            bf16x8 pa = *(const bf16x8*)(pts + (w * 16 + l15) * 456 + nt * 64 + kc * 32 + lg * 8);
            #pragma unroll
            for (int dsub = 0; dsub < 4; ++dsub) {
                int row = dsub * 16 + l15;
                bf16x8 vb = *(const bf16x8*)(kcur + row * 64 + (((kc * 4 + lg) ^ (row & 7)) << 3));
                o[dsub] = __builtin_amdgcn_mfma_f32_16x16x32_bf16(pa, vb, o[dsub], 0, 0, 0);
            }
        }
        __builtin_amdgcn_s_setprio(0);
        if (nt < 6) {
            #pragma unroll
            for (int i = 0; i < 2; ++i) *(bf16x8*)(&kvs[(nt + 1) & 1][swoff[i]]) = ra[i];
        }
        __syncthreads();
    }

    // ---------------- store (normalize here) ----------------
    #pragma unroll
    for (int dsub = 0; dsub < 4; ++dsub)
        #pragma unroll
        for (int rr = 0; rr < 4; ++rr) {
            int p = p0w + lg * 4 + rr;
            if (p < P_)
                Obuf[((size_t)b * P_ + p) * C_ + h * HD_ + dsub * 16 + l15] =
                    f2bf(o[dsub][rr] * rinv4[rr]);
        }
}

// ---------------------------------------------------------------------------
extern "C" void kernel_launch(void* const* d_in, const int* in_sizes, int n_in,
                              void* d_out, int out_size, void* d_ws, size_t ws_size,
                              hipStream_t stream)
{
    const float* x         = (const float*)d_in[0];
    const float* q_learned = (const float*)d_in[1];
    const float* pos_embed = (const float*)d_in[2];
    const float* wk        = (const float*)d_in[3];
    const float* wv        = (const float*)d_in[4];
    const float* rpe_w     = (const float*)d_in[5];
    const float* proj_w    = (const float*)d_in[6];
    const float* proj_b    = (const float*)d_in[7];
    const int*   rp_bucket = (const int*)d_in[8];
    float* out = (float*)d_out;

    char* ws = (char*)d_ws;
    u16*   xh    = (u16*)(ws);                        // 38,633,472 B
    u16*   wkvh  = (u16*)(ws + 38633472);             //  2,359,296 B
    u16*   pwh   = (u16*)(ws + 40992768);             //  1,179,648 B
    u16*   qh    = (u16*)(ws + 42172416);             //    302,592 B
    float* lk    = (float*)(ws + 42475008);           //     75,776 B
    float* biasT = (float*)(ws + 42550784);           //  4,153,344 B
    u16*   Kh    = (u16*)(ws + 46704128);             // 38,633,472 B
    u16*   Vt    = (u16*)(ws + 85337600);             // 44,040,192 B
    u16*   Obuf  = (u16*)(ws + 129377792);            // 19,365,888 B (end ~148.7 MB)

    conv_all<<<20592, 256, 0, stream>>>(x, wk, wv, proj_w, xh, wkvh, pwh);

    prep1_kernel<<<P_, 256, 0, stream>>>(q_learned, pos_embed, rpe_w, qh, lk);
    prep2_kernel<<<H_ * N_, 256, 0, stream>>>(lk, rp_bucket, biasT);

    vzero_kernel<<<12288, 256, 0, stream>>>(Vt);

    dim3 gkv(1536 / 128, (M_KV + 127) / 128);   // 12 x 197
    gemm_kv<<<gkv, 256, 0, stream>>>(xh, wkvh, Kh, Vt);

    attn_mfma5<<<3072, 256, 0, stream>>>(qh, Kh, Vt, biasT, Obuf);

    dim3 gpr(768 / 128, (M_PR + 127) / 128);    // 6 x 99
    gemm_proj<<<gpr, 256, 0, stream>>>(Obuf, pwh, out, proj_b);
}

// Round 11
// 239.079 us; speedup vs baseline: 1.1463x; 1.1463x over previous
//
#include <hip/hip_runtime.h>

typedef unsigned short u16;
typedef short bf16x8 __attribute__((ext_vector_type(8)));
typedef float f32x4 __attribute__((ext_vector_type(4)));
typedef const __attribute__((address_space(1))) void* gptr_t;
typedef __attribute__((address_space(3))) void* lptr_t;

#define B_   64
#define N_   393
#define C_   768
#define H_   12
#define HD_  64
#define P_   197
#define BIAS_N 416
#define PPAD 208
#define VTP  448
#define M_KV (B_ * N_)   // 25152
#define M_PR (B_ * P_)   // 12608
#define SCALE_L2E 0.180336879f   // 0.125 * log2(e)

__device__ __forceinline__ u16 f2bf(float f) {
    unsigned u = __float_as_uint(f);
    return (u16)((u + 0x7FFFu + ((u >> 16) & 1u)) >> 16);
}
__device__ __forceinline__ unsigned cvt_pk_bf16(float lo, float hi) {
    unsigned r;
    asm("v_cvt_pk_bf16_f32 %0, %1, %2" : "=v"(r) : "v"(lo), "v"(hi));
    return r;
}
__device__ __forceinline__ float exp2_fast(float x) {
    float r;
    asm("v_exp_f32 %0, %1" : "=v"(r) : "v"(x));
    return r;
}

// ---------------------------------------------------------------------------
// conv_all: fused fp32->bf16 for x, wk, wv, proj_w (one launch)
// ---------------------------------------------------------------------------
__global__ __launch_bounds__(256) void conv_all(
    const float* __restrict__ x, const float* __restrict__ wk,
    const float* __restrict__ wv, const float* __restrict__ pw,
    u16* __restrict__ xh, u16* __restrict__ wkvh, u16* __restrict__ pwh)
{
    const int XN4 = 19316736 / 4;
    const int WN4 = 589824 / 4;
    int i = blockIdx.x * 256 + threadIdx.x;
    const float* src; u16* dst; int off;
    if (i < XN4) { src = x; dst = xh; off = i; }
    else {
        int j = i - XN4;
        int sec = j / WN4;
        off = j - sec * WN4;
        src = sec == 0 ? wk : (sec == 1 ? wv : pw);
        dst = sec == 0 ? wkvh : (sec == 1 ? wkvh + 589824 : pwh);
    }
    float4 v = ((const float4*)src)[off];
    u16 o[4] = {f2bf(v.x), f2bf(v.y), f2bf(v.z), f2bf(v.w)};
    *(uint2*)(dst + off * 4) = *(uint2*)o;
}

// ---------------------------------------------------------------------------
// prep1: q = q_learned + pos_embed -> qh (bf16 [P][C]); lk[h][p][8] fp32
// ---------------------------------------------------------------------------
__global__ __launch_bounds__(256) void prep1_kernel(
    const float* __restrict__ q_learned, const float* __restrict__ pos_embed,
    const float* __restrict__ rpe_w, u16* __restrict__ qh, float* __restrict__ lk)
{
    __shared__ float q_s[C_];
    const int p = blockIdx.x, t = threadIdx.x;
    for (int c = t; c < C_; c += 256) {
        float v = q_learned[c] + pos_embed[p * C_ + c];
        q_s[c] = v;
        qh[p * C_ + c] = f2bf(v);
    }
    __syncthreads();
    if (t < H_ * 8) {
        int h = t >> 3, u = t & 7;
        float s = 0.f;
        #pragma unroll 8
        for (int d = 0; d < HD_; ++d)
            s = fmaf(q_s[h * HD_ + d], rpe_w[d * 8 + u], s);
        lk[(h * P_ + p) * 8 + u] = s;
    }
}

// ---------------------------------------------------------------------------
// prep2: biasT[h][j][p] = lk[h][p][bucket] * log2(e)   (pre-scaled for exp2)
// ---------------------------------------------------------------------------
__global__ __launch_bounds__(256) void prep2_kernel(
    const float* __restrict__ lk, const int* __restrict__ rp_bucket,
    float* __restrict__ biasT)
{
    int bx = blockIdx.x;
    int h = bx / N_, j = bx % N_;
    int t = threadIdx.x;
    if (t >= PPAD) return;
    int jm;
    if (j == 0) jm = 0;
    else { jm = j - 1; if (jm >= 196) jm -= 196; jm += 1; }
    float v = 0.f;
    if (t < P_) {
        int bucket = rp_bucket[t * P_ + jm];
        v = lk[(h * P_ + t) * 8 + bucket] * 1.44269504f;
    }
    biasT[((size_t)h * BIAS_N + j) * PPAD + t] = v;
}

// ---------------------------------------------------------------------------
// Templated 128x128x64 bf16 MFMA GEMM, m97 structure (known-good, 91 us):
// global_load_lds(16B) into linear LDS [128][64], 2-barrier K-loop,
// bijective XCD swizzle, dense coalesced epilogue.
// ---------------------------------------------------------------------------
template <bool F32OUT>
__global__ __launch_bounds__(256) void gemm_bf16(
    const u16* __restrict__ A, const u16* __restrict__ Bw,
    u16* __restrict__ Cb, float* __restrict__ Cf, const float* __restrict__ bias,
    int M, int ldc)
{
    __shared__ __align__(16) u16 As[128 * 64];
    __shared__ __align__(16) u16 Bs[128 * 64];

    const int gx = gridDim.x;
    const int nwg = gx * gridDim.y;
    const int orig = blockIdx.y * gx + blockIdx.x;
    const int xcd = orig & 7, rank = orig >> 3;
    const int q = nwg >> 3, r = nwg & 7;
    const int wgid = (xcd < r ? xcd * (q + 1) : r * (q + 1) + (xcd - r) * q) + rank;
    const int n0 = (wgid % gx) * 128;
    const int m0 = (wgid / gx) * 128;

    const int t = threadIdx.x;
    const int w = t >> 6, l = t & 63;
    const int wr = w >> 1, wc = w & 1;
    const int l15 = l & 15, lg = l >> 4;
    const int lrow = l >> 3, lslot = l & 7;
    const int Mc = M - 1;

    f32x4 acc[4][4];
    #pragma unroll
    for (int i = 0; i < 4; ++i)
        #pragma unroll
        for (int j = 0; j < 4; ++j) acc[i][j] = (f32x4){0.f, 0.f, 0.f, 0.f};

    for (int ks = 0; ks < 12; ++ks) {
        const int k0 = ks * 64;
        if (ks) __syncthreads();          // previous tile fully consumed
        #pragma unroll
        for (int i = 0; i < 4; ++i) {
            const int rbase = w * 32 + i * 8;        // 8 rows per issue
            int arow = m0 + rbase + lrow; if (arow > Mc) arow = Mc;
            const int brow = n0 + rbase + lrow;
            const u16* ga = A  + (size_t)arow * 768 + k0 + lslot * 8;
            const u16* gb = Bw + (size_t)brow * 768 + k0 + lslot * 8;
            __builtin_amdgcn_global_load_lds((gptr_t)(const void*)ga,
                                             (lptr_t)(void*)(As + rbase * 64), 16, 0, 0);
            __builtin_amdgcn_global_load_lds((gptr_t)(const void*)gb,
                                             (lptr_t)(void*)(Bs + rbase * 64), 16, 0, 0);
        }
        __syncthreads();                  // drains vmcnt: tile resident
        #pragma unroll
        for (int kk = 0; kk < 2; ++kk) {
            bf16x8 af[4], bfr[4];
            #pragma unroll
            for (int mf = 0; mf < 4; ++mf) {
                af[mf]  = *(const bf16x8*)(As + (wr * 64 + mf * 16 + l15) * 64 + (kk * 4 + lg) * 8);
                bfr[mf] = *(const bf16x8*)(Bs + (wc * 64 + mf * 16 + l15) * 64 + (kk * 4 + lg) * 8);
            }
            #pragma unroll
            for (int mf = 0; mf < 4; ++mf)
                #pragma unroll
                for (int nf = 0; nf < 4; ++nf)
                    acc[mf][nf] = __builtin_amdgcn_mfma_f32_16x16x32_bf16(
                        af[mf], bfr[nf], acc[mf][nf], 0, 0, 0);
        }
    }

    #pragma unroll
    for (int mf = 0; mf < 4; ++mf) {
        #pragma unroll
        for (int nf = 0; nf < 4; ++nf) {
            int col = n0 + wc * 64 + nf * 16 + l15;
            float bb = 0.f;
            if (F32OUT) bb = bias[col];
            #pragma unroll
            for (int rr = 0; rr < 4; ++rr) {
                int m = m0 + wr * 64 + mf * 16 + lg * 4 + rr;
                if (m < M) {
                    if (F32OUT) Cf[(size_t)m * ldc + col] = acc[mf][nf][rr] + bb;
                    else        Cb[(size_t)m * ldc + col] = f2bf(acc[mf][nf][rr]);
                }
            }
        }
    }
}

// ---------------------------------------------------------------------------
// vtrans: Vt[b][h][d][j(448)] = KV[b*393+j][768 + h*64 + d]  (j>=393 -> 0)
// Coalesced 16B writes; reads absorbed by L2.
// ---------------------------------------------------------------------------
__global__ __launch_bounds__(256) void vtrans_kernel(const u16* __restrict__ KV,
                                                     u16* __restrict__ Vt)
{
    const int bh = blockIdx.x;
    const int b = bh / H_, h = bh % H_;
    const int t = threadIdx.x, w = t >> 6, l = t & 63;
    const int d = w * 16 + (l >> 2);
    const int c = l & 3;
    const u16* src = KV + (size_t)b * N_ * 1536 + 768 + h * HD_ + d;
    u16* dst = Vt + (size_t)(bh * HD_ + d) * VTP;
    for (int jb = 0; jb < VTP; jb += 32) {
        int j0 = jb + c * 8;
        u16 v[8];
        #pragma unroll
        for (int i = 0; i < 8; ++i) {
            int j = j0 + i;
            v[i] = (j < N_) ? src[(size_t)j * 1536] : (u16)0;
        }
        *(bf16x8*)(dst + j0) = *(bf16x8*)v;
    }
}

// ---------------------------------------------------------------------------
// attention v5 (r9 trim, dense KV): block = (b, h, 64-row p-tile).
// Tile 6 (n=384..392): 1/4 subs in QK^T/softmax, kc0-only PV.
// ---------------------------------------------------------------------------
__global__ __launch_bounds__(256, 2) void attn_mfma5(
    const u16* __restrict__ qh, const u16* __restrict__ KV,
    const u16* __restrict__ Vt, const float* __restrict__ biasT,
    u16* __restrict__ Obuf)
{
    __shared__ __align__(16) u16 pts[64 * 456];
    __shared__ __align__(16) u16 kvs[2][64 * 64];

    const int id = blockIdx.x;
    const int work = (id & 7) * 384 + (id >> 3);
    const int ptile = work & 3;
    const int rest = work >> 2;
    const int h = rest % 12;
    const int b = rest / 12;
    const int p0 = ptile * 64;

    const int t = threadIdx.x, w = t >> 6, l = t & 63;
    const int l15 = l & 15, lg = l >> 4;
    const int p0w = p0 + w * 16;

    int srow[2], sslot[2], swoff[2];
    #pragma unroll
    for (int i = 0; i < 2; ++i) {
        int c = t + 256 * i;
        srow[i] = c >> 3; sslot[i] = c & 7;
        swoff[i] = srow[i] * 64 + ((sslot[i] ^ (srow[i] & 7)) << 3);
    }

    int prow = p0w + l15; if (prow > P_ - 1) prow = P_ - 1;
    const u16* qp = qh + (size_t)prow * C_ + h * HD_ + lg * 8;
    bf16x8 qf0 = *(const bf16x8*)(qp);
    bf16x8 qf1 = *(const bf16x8*)(qp + 32);

    const u16* Kbase = KV + (size_t)b * (N_ * 1536) + h * HD_;
    const u16* Vbase = Vt + (size_t)(b * H_ + h) * (HD_ * VTP);

    f32x4 acc[7][4];
    #pragma unroll
    for (int i = 0; i < 7; ++i)
        #pragma unroll
        for (int j = 0; j < 4; ++j) acc[i][j] = (f32x4){0.f, 0.f, 0.f, 0.f};

    // ---------------- pass 1: QK^T ----------------
    bf16x8 ra[2];
    #pragma unroll
    for (int i = 0; i < 2; ++i)
        ra[i] = *(const bf16x8*)(Kbase + (size_t)srow[i] * 1536 + sslot[i] * 8);
    #pragma unroll
    for (int i = 0; i < 2; ++i) *(bf16x8*)(&kvs[0][swoff[i]]) = ra[i];
    __syncthreads();

    #pragma unroll
    for (int nt = 0; nt < 7; ++nt) {
        const u16* kcur = kvs[nt & 1];
        if (nt < 6) {
            #pragma unroll
            for (int i = 0; i < 2; ++i) {
                int rn = (nt + 1) * 64 + srow[i]; if (rn > N_ - 1) rn = N_ - 1;
                ra[i] = *(const bf16x8*)(Kbase + (size_t)rn * 1536 + sslot[i] * 8);
            }
        }
        const int smax = (nt == 6) ? 1 : 4;
        __builtin_amdgcn_s_setprio(1);
        #pragma unroll
        for (int kc = 0; kc < 2; ++kc)
            #pragma unroll
            for (int sub = 0; sub < smax; ++sub) {
                int row = sub * 16 + l15;
                bf16x8 kb = *(const bf16x8*)(kcur + row * 64 + (((kc * 4 + lg) ^ (row & 7)) << 3));
                acc[nt][sub] = __builtin_amdgcn_mfma_f32_16x16x32_bf16(
                    kc ? qf1 : qf0, kb, acc[nt][sub], 0, 0, 0);
            }
        __builtin_amdgcn_s_setprio(0);
        if (nt < 6) {
            #pragma unroll
            for (int i = 0; i < 2; ++i) *(bf16x8*)(&kvs[(nt + 1) & 1][swoff[i]]) = ra[i];
        }
        __syncthreads();
    }

    // issue V tile 0 loads; softmax hides latency (T14)
    #pragma unroll
    for (int i = 0; i < 2; ++i)
        ra[i] = *(const bf16x8*)(Vbase + (size_t)srow[i] * VTP + sslot[i] * 8);

    // ---------------- single-pass softmax ----------------
    const int pcl = (p0w + lg * 4) > (PPAD - 4) ? (PPAD - 4) : (p0w + lg * 4);
    float s4[4] = {0.f, 0.f, 0.f, 0.f};
    #pragma unroll
    for (int nt = 0; nt < 7; ++nt) {
        const int smax = (nt == 6) ? 1 : 4;
        #pragma unroll
        for (int sub = 0; sub < smax; ++sub) {
            int n = nt * 64 + sub * 16 + l15;
            if (n < N_) {
                float4 b4 = *(const float4*)(biasT + ((size_t)h * BIAS_N + n) * PPAD + pcl);
                float bb[4] = {b4.x, b4.y, b4.z, b4.w};
                #pragma unroll
                for (int rr = 0; rr < 4; ++rr) {
                    float e = exp2_fast(fmaf(acc[nt][sub][rr], SCALE_L2E, bb[rr]));
                    acc[nt][sub][rr] = e;
                    s4[rr] += e;
                }
            } else {
                acc[nt][sub] = (f32x4){0.f, 0.f, 0.f, 0.f};
            }
        }
    }
    float rinv4[4];
    #pragma unroll
    for (int rr = 0; rr < 4; ++rr) {
        float s = s4[rr];
        s += __shfl_xor(s, 1); s += __shfl_xor(s, 2);
        s += __shfl_xor(s, 4); s += __shfl_xor(s, 8);
        rinv4[rr] = 1.0f / s;
    }

    // ---------------- P (unnormalized) -> LDS bf16 ----------------
    {
        const int rowb = w * 16 + lg * 4;
        #pragma unroll
        for (int nt = 0; nt < 7; ++nt) {
            const int smax = (nt == 6) ? 1 : 4;
            #pragma unroll
            for (int sub = 0; sub < smax; ++sub) {
                int col = nt * 64 + sub * 16 + l15;
                unsigned pk01 = cvt_pk_bf16(acc[nt][sub][0], acc[nt][sub][1]);
                unsigned pk23 = cvt_pk_bf16(acc[nt][sub][2], acc[nt][sub][3]);
                pts[(rowb + 0) * 456 + col] = (u16)pk01;
                pts[(rowb + 1) * 456 + col] = (u16)(pk01 >> 16);
                pts[(rowb + 2) * 456 + col] = (u16)pk23;
                pts[(rowb + 3) * 456 + col] = (u16)(pk23 >> 16);
            }
        }
        // zero P cols 400-415 (read by PV tail kc0); 416-447 never read
        #pragma unroll
        for (int rr = 0; rr < 4; ++rr)
            pts[(rowb + rr) * 456 + 400 + l15] = 0;
    }
    #pragma unroll
    for (int i = 0; i < 2; ++i) *(bf16x8*)(&kvs[0][swoff[i]]) = ra[i];
    __syncthreads();

    // ---------------- pass 2: PV ----------------
    f32x4 o[4];
    #pragma unroll
    for (int i = 0; i < 4; ++i) o[i] = (f32x4){0.f, 0.f, 0.f, 0.f};

    #pragma unroll
    for (int nt = 0; nt < 7; ++nt) {
        const u16* kcur = kvs[nt & 1];
        if (nt < 6) {
            #pragma unroll
            for (int i = 0; i < 2; ++i)
                ra[i] = *(const bf16x8*)(Vbase + (size_t)srow[i] * VTP + (nt + 1) * 64 + sslot[i] * 8);
        }
        const int kcmax = (nt == 6) ? 1 : 2;
        __builtin_amdgcn_s_setprio(1);
        #pragma unroll
        for (int kc = 0; kc < kcmax; ++kc) {
            bf16x8 pa = *(const bf16x8*)(pts + (w * 16 + l15) * 456 + nt * 64 + kc * 32 + lg * 8);
            #pragma unroll
            for (int dsub = 0; dsub < 4; ++dsub) {
                int row = dsub * 16 + l15;
                bf16x8 vb = *(const bf16x8*)(kcur + row * 64 + (((kc * 4 + lg) ^ (row & 7)) << 3));
                o[dsub] = __builtin_amdgcn_mfma_f32_16x16x32_bf16(pa, vb, o[dsub], 0, 0, 0);
            }
        }
        __builtin_amdgcn_s_setprio(0);
        if (nt < 6) {
            #pragma unroll
            for (int i = 0; i < 2; ++i) *(bf16x8*)(&kvs[(nt + 1) & 1][swoff[i]]) = ra[i];
        }
        __syncthreads();
    }

    // ---------------- store (normalize here) ----------------
    #pragma unroll
    for (int dsub = 0; dsub < 4; ++dsub)
        #pragma unroll
        for (int rr = 0; rr < 4; ++rr) {
            int p = p0w + lg * 4 + rr;
            if (p < P_)
                Obuf[((size_t)b * P_ + p) * C_ + h * HD_ + dsub * 16 + l15] =
                    f2bf(o[dsub][rr] * rinv4[rr]);
        }
}

// ---------------------------------------------------------------------------
extern "C" void kernel_launch(void* const* d_in, const int* in_sizes, int n_in,
                              void* d_out, int out_size, void* d_ws, size_t ws_size,
                              hipStream_t stream)
{
    const float* x         = (const float*)d_in[0];
    const float* q_learned = (const float*)d_in[1];
    const float* pos_embed = (const float*)d_in[2];
    const float* wk        = (const float*)d_in[3];
    const float* wv        = (const float*)d_in[4];
    const float* rpe_w     = (const float*)d_in[5];
    const float* proj_w    = (const float*)d_in[6];
    const float* proj_b    = (const float*)d_in[7];
    const int*   rp_bucket = (const int*)d_in[8];
    float* out = (float*)d_out;

    char* ws = (char*)d_ws;
    u16*   xh    = (u16*)(ws);                        // 38,633,472 B
    u16*   wkvh  = (u16*)(ws + 38633472);             //  2,359,296 B
    u16*   pwh   = (u16*)(ws + 40992768);             //  1,179,648 B
    u16*   qh    = (u16*)(ws + 42172416);             //    302,592 B
    float* lk    = (float*)(ws + 42475008);           //     75,776 B
    float* biasT = (float*)(ws + 42550784);           //  4,153,344 B
    u16*   KV    = (u16*)(ws + 46704128);             // 77,266,944 B
    u16*   Vt    = (u16*)(ws + 123971072);            // 44,040,192 B
    u16*   Obuf  = (u16*)(ws + 168011264);            // 19,365,888 B (end ~179 MB)

    conv_all<<<20592, 256, 0, stream>>>(x, wk, wv, proj_w, xh, wkvh, pwh);

    prep1_kernel<<<P_, 256, 0, stream>>>(q_learned, pos_embed, rpe_w, qh, lk);
    prep2_kernel<<<H_ * N_, 256, 0, stream>>>(lk, rp_bucket, biasT);

    dim3 gkv(1536 / 128, (M_KV + 127) / 128);   // 12 x 197
    gemm_bf16<false><<<gkv, 256, 0, stream>>>(xh, wkvh, KV, nullptr, nullptr, M_KV, 1536);

    vtrans_kernel<<<B_ * H_, 256, 0, stream>>>(KV, Vt);

    attn_mfma5<<<3072, 256, 0, stream>>>(qh, KV, Vt, biasT, Obuf);

    dim3 gpr(768 / 128, (M_PR + 127) / 128);    // 6 x 99
    gemm_bf16<true><<<gpr, 256, 0, stream>>>(Obuf, pwh, nullptr, out, proj_b, M_PR, 768);
}